// Round 7
// baseline (2077.393 us; speedup 1.0000x reference)
//
#include <hip/hip_runtime.h>

#define N_      50000
#define E_      800000
#define HC_     128
#define ED_     44
#define NH_     4
#define DEGCAP_ 96    // Poisson(16); P(deg>96) astronomically small
#define CHK_    8     // edges per chunk-wave
#define LCAP_   (E_ / CHK_ + N_)   // worst-case chunk count

// ---------------- x @ W[mat] + b : 32-row tile, one mat per block (grid.y)
__global__ __launch_bounds__(256) void k_lin(
    const float* __restrict__ x,
    const float* __restrict__ Wq, const float* __restrict__ bq,
    const float* __restrict__ Wk, const float* __restrict__ bk,
    const float* __restrict__ Wv, const float* __restrict__ bv,
    const float* __restrict__ Wsk, const float* __restrict__ bsk,
    float* __restrict__ q, float* __restrict__ k, float* __restrict__ v,
    float* __restrict__ skip)
{
    __shared__ float xs[32 * 128];    // 16 KB
    const int n0 = blockIdx.x * 32;
    const int t  = threadIdx.x;

    #pragma unroll
    for (int i = 0; i < 4; ++i) {
        int idx = t + i * 256;        // float4 index, 0..1023
        int row = idx >> 5;
        float4 a = make_float4(0.f, 0.f, 0.f, 0.f);
        if (n0 + row < N_) a = ((const float4*)x)[(size_t)n0 * 32 + idx];
        *(float4*)&xs[idx * 4] = a;
    }
    __syncthreads();

    const float* Wm[4] = {Wq, Wk, Wv, Wsk};
    const float* bm[4] = {bq, bk, bv, bsk};
    float* om[4] = {q, k, v, skip};
    const int mat = blockIdx.y;
    const float* W = Wm[mat];

    const int tx = t & 31, ty = t >> 5;
    float acc[4][4];
    #pragma unroll
    for (int r = 0; r < 4; ++r) {
        acc[r][0] = 0.f; acc[r][1] = 0.f; acc[r][2] = 0.f; acc[r][3] = 0.f;
    }

    float4 wb[4];
    #pragma unroll
    for (int dd = 0; dd < 4; ++dd)
        wb[dd] = *(const float4*)(W + dd * 128 + tx * 4);

    for (int s = 0; s < 32; ++s) {
        int sn = (s + 1) & 31;
        float4 wn[4];
        #pragma unroll
        for (int dd = 0; dd < 4; ++dd)
            wn[dd] = *(const float4*)(W + (sn * 4 + dd) * 128 + tx * 4);
        #pragma unroll
        for (int r = 0; r < 4; ++r) {
            float4 xv = *(const float4*)&xs[(ty * 4 + r) * 128 + s * 4];
            acc[r][0] += xv.x * wb[0].x + xv.y * wb[1].x + xv.z * wb[2].x + xv.w * wb[3].x;
            acc[r][1] += xv.x * wb[0].y + xv.y * wb[1].y + xv.z * wb[2].y + xv.w * wb[3].y;
            acc[r][2] += xv.x * wb[0].z + xv.y * wb[1].z + xv.z * wb[2].z + xv.w * wb[3].z;
            acc[r][3] += xv.x * wb[0].w + xv.y * wb[1].w + xv.z * wb[2].w + xv.w * wb[3].w;
        }
        #pragma unroll
        for (int dd = 0; dd < 4; ++dd) wb[dd] = wn[dd];
    }

    float4 b4 = *(const float4*)(bm[mat] + tx * 4);
    float* o = om[mat];
    #pragma unroll
    for (int r = 0; r < 4; ++r) {
        int n = n0 + ty * 4 + r;
        if (n < N_) {
            float4 rr = make_float4(acc[r][0] + b4.x, acc[r][1] + b4.y,
                                    acc[r][2] + b4.z, acc[r][3] + b4.w);
            ((float4*)(o + (size_t)n * 128))[tx] = rr;
        }
    }
}

// --------------------------- padded-CSR build: edge-id only (src via ei)
__global__ __launch_bounds__(256) void k_scatter(const int* __restrict__ ei,
                                                 int* __restrict__ cnt,
                                                 int* __restrict__ csr) {
    int e = blockIdx.x * 256 + threadIdx.x;   // E_ divisible by 256
    int dst = ei[E_ + e];
    int pos = atomicAdd(&cnt[dst], 1);
    if (pos < DEGCAP_) csr[(size_t)dst * DEGCAP_ + pos] = e;
}

// ---------------- compact (node,chunk) worklist: one wave per 8 edges
__global__ __launch_bounds__(256) void k_chunks(const int* __restrict__ cnt,
                                                int* __restrict__ chcnt,
                                                int* __restrict__ chlist) {
    int n = blockIdx.x * 256 + threadIdx.x;
    if (n >= N_) return;
    int deg = cnt[n];
    deg = deg < DEGCAP_ ? deg : DEGCAP_;
    int nc = (deg + CHK_ - 1) / CHK_;
    if (nc == 0) return;
    int pos = atomicAdd(chcnt, nc);
    for (int j = 0; j < nc; ++j) chlist[pos + j] = (n << 4) | j;
}

// ------------- chunk-parallel deferred-normalization aggregation.
// One wave per (node, 8-edge chunk): ~125k active waves (vs 50k node-waves)
// so gather latency is hidden by TLP, not by intra-wave scheduling (which
// rounds 1/4/6 showed the compiler defeats). 512-thr blocks pack 8 waves
// per workgroup slot (occupancy was WG-slot-capped at ~2.5 WGs/CU).
// Partial sums (w*v [128], w*ea [4][44], w [4]) accumulate via atomicAdd
// (pure segment sum thanks to deferred softmax normalization; exp clamped).
// Per-node We contraction + normalize + skip moved to k_fin.
__global__ __launch_bounds__(512) void k_node(
    const int* __restrict__ chcnt, const int* __restrict__ chlist,
    const int* __restrict__ cnt, const int* __restrict__ csr,
    const int* __restrict__ ei, const float* __restrict__ ea,
    const float* __restrict__ We, const float* __restrict__ q,
    const float* __restrict__ k, const float* __restrict__ v,
    float* __restrict__ sav, float* __restrict__ sae,
    float* __restrict__ sbuf)
{
    __shared__ float sq [8][128];   // q-row staging (wave-private)
    __shared__ float sqw[8][176];   // qwe[h][d], stride 44
    const int t = threadIdx.x, w = t >> 6, l = t & 63;
    const int id = blockIdx.x * 8 + w;
    if (id >= chcnt[0]) return;     // wave-uniform exit
    const int p = chlist[id];
    const int n = p >> 4, c = p & 15;

    // ---- stage q row
    float2 q2 = ((const float2*)(q + (size_t)n * HC_))[l];
    ((float2*)&sq[w][0])[l] = q2;

    // ---- inline qWe: lane (h=l>>4, i16=l&15) -> dims 3*i16..+2 of head h
    {
        const int h = l >> 4, i16 = l & 15;
        const int d0 = 3 * i16;
        const int de0 = (d0     < ED_) ? d0     : ED_ - 1;
        const int de1 = (d0 + 1 < ED_) ? d0 + 1 : ED_ - 1;
        const int de2 = (d0 + 2 < ED_) ? d0 + 2 : ED_ - 1;
        const float* qh  = &sq[w][h * 32];
        const float* w0p = We + de0 * HC_ + h * 32;
        const float* w1p = We + de1 * HC_ + h * 32;
        const float* w2p = We + de2 * HC_ + h * 32;
        float qw0 = 0.f, qw1 = 0.f, qw2 = 0.f;
        #pragma unroll
        for (int i = 0; i < 8; ++i) {
            float4 q4 = *(const float4*)(qh  + i * 4);
            float4 a0 = *(const float4*)(w0p + i * 4);
            float4 a1 = *(const float4*)(w1p + i * 4);
            float4 a2 = *(const float4*)(w2p + i * 4);
            qw0 += q4.x*a0.x + q4.y*a0.y + q4.z*a0.z + q4.w*a0.w;
            qw1 += q4.x*a1.x + q4.y*a1.y + q4.z*a1.z + q4.w*a1.w;
            qw2 += q4.x*a2.x + q4.y*a2.y + q4.z*a2.z + q4.w*a2.w;
        }
        if (d0     < ED_) sqw[w][h * ED_ + d0]     = qw0;
        if (d0 + 1 < ED_) sqw[w][h * ED_ + d0 + 1] = qw1;
        if (d0 + 2 < ED_) sqw[w][h * ED_ + d0 + 2] = qw2;
    }

    // ---- lane roles: g=l>>4 (edge in half-chunk), eh=head, si=sublane
    const int g = l >> 4, ii = l & 15, eh = ii >> 2, si = ii & 3;
    const float4 qa = *(const float4*)&sq[w][eh * 32 + si * 8];
    const float4 qb = *(const float4*)&sq[w][eh * 32 + si * 8 + 4];
    float4 w0, w1, w2;
    {   // qwe fragment: si<3 -> dims [si*12,+12); si==3 -> [36,+8) + zero
        const float* wp = &sqw[w][eh * ED_ + si * 12];
        w0 = *(const float4*)wp;
        w1 = *(const float4*)(wp + 4);
        w2 = (si < 3) ? *(const float4*)(wp + 8) : make_float4(0.f,0.f,0.f,0.f);
    }
    const int eoff2 = (si < 3) ? si * 12 + 8 : 36;

    int deg = cnt[n];
    deg = deg < DEGCAP_ ? deg : DEGCAP_;
    const int rem = deg - c * CHK_;           // 1..96; chunk holds min(rem,8)

    // lane j (j = l&7) holds slot c*8+j of this node's CSR row
    int idx = c * CHK_ + (l & 7);
    if (idx >= deg) idx = deg - 1;
    const int eId  = csr[(size_t)n * DEGCAP_ + idx];
    const int srcN = ei[eId];

    const int slotA = g, slotB = 4 + g;
    const int sA = __shfl(srcN, slotA), eEA = __shfl(eId, slotA);
    const int sB = __shfl(srcN, slotB), eEB = __shfl(eId, slotB);

    // ---------- load block: 14 independent float4 gathers
    const float* kpA = k + (size_t)sA * HC_ + eh * 32 + si * 8;
    const float* vpA = v + (size_t)sA * HC_ + eh * 32 + si * 8;
    const float* epA = ea + (size_t)eEA * ED_;
    const float* kpB = k + (size_t)sB * HC_ + eh * 32 + si * 8;
    const float* vpB = v + (size_t)sB * HC_ + eh * 32 + si * 8;
    const float* epB = ea + (size_t)eEB * ED_;
    const float4 kaA = *(const float4*)kpA;
    const float4 kbA = *(const float4*)(kpA + 4);
    const float4 vaA = *(const float4*)vpA;
    const float4 vbA = *(const float4*)(vpA + 4);
    const float4 e0A = *(const float4*)(epA + si * 12);
    const float4 e1A = *(const float4*)(epA + si * 12 + 4);
    const float4 e2A = *(const float4*)(epA + eoff2);
    const float4 kaB = *(const float4*)kpB;
    const float4 kbB = *(const float4*)(kpB + 4);
    const float4 vaB = *(const float4*)vpB;
    const float4 vbB = *(const float4*)(vpB + 4);
    const float4 e0B = *(const float4*)(epB + si * 12);
    const float4 e1B = *(const float4*)(epB + si * 12 + 4);
    const float4 e2B = *(const float4*)(epB + eoff2);

    float pA = qa.x*kaA.x + qa.y*kaA.y + qa.z*kaA.z + qa.w*kaA.w
             + qb.x*kbA.x + qb.y*kbA.y + qb.z*kbA.z + qb.w*kbA.w
             + w0.x*e0A.x + w0.y*e0A.y + w0.z*e0A.z + w0.w*e0A.w
             + w1.x*e1A.x + w1.y*e1A.y + w1.z*e1A.z + w1.w*e1A.w
             + w2.x*e2A.x + w2.y*e2A.y + w2.z*e2A.z + w2.w*e2A.w;
    float pB = qa.x*kaB.x + qa.y*kaB.y + qa.z*kaB.z + qa.w*kaB.w
             + qb.x*kbB.x + qb.y*kbB.y + qb.z*kbB.z + qb.w*kbB.w
             + w0.x*e0B.x + w0.y*e0B.y + w0.z*e0B.z + w0.w*e0B.w
             + w1.x*e1B.x + w1.y*e1B.y + w1.z*e1B.z + w1.w*e1B.w
             + w2.x*e2B.x + w2.y*e2B.y + w2.z*e2B.z + w2.w*e2B.w;
    pA += __shfl_xor(pA, 1);  pB += __shfl_xor(pB, 1);
    pA += __shfl_xor(pA, 2);  pB += __shfl_xor(pB, 2);
    const float alA = fminf(pA * 0.17677669529663687f, 40.f);
    const float alB = fminf(pB * 0.17677669529663687f, 40.f);
    const float wjA = (slotA < rem) ? __expf(alA) : 0.f;
    const float wjB = (slotB < rem) ? __expf(alB) : 0.f;

    float ssum = wjA + wjB;
    float4 av0, av1, aeA, aeB, aeC;
    av0.x = wjA * vaA.x + wjB * vaB.x;  av0.y = wjA * vaA.y + wjB * vaB.y;
    av0.z = wjA * vaA.z + wjB * vaB.z;  av0.w = wjA * vaA.w + wjB * vaB.w;
    av1.x = wjA * vbA.x + wjB * vbB.x;  av1.y = wjA * vbA.y + wjB * vbB.y;
    av1.z = wjA * vbA.z + wjB * vbB.z;  av1.w = wjA * vbA.w + wjB * vbB.w;
    aeA.x = wjA * e0A.x + wjB * e0B.x;  aeA.y = wjA * e0A.y + wjB * e0B.y;
    aeA.z = wjA * e0A.z + wjB * e0B.z;  aeA.w = wjA * e0A.w + wjB * e0B.w;
    aeB.x = wjA * e1A.x + wjB * e1B.x;  aeB.y = wjA * e1A.y + wjB * e1B.y;
    aeB.z = wjA * e1A.z + wjB * e1B.z;  aeB.w = wjA * e1A.w + wjB * e1B.w;
    aeC.x = wjA * e2A.x + wjB * e2B.x;  aeC.y = wjA * e2A.y + wjB * e2B.y;
    aeC.z = wjA * e2A.z + wjB * e2B.z;  aeC.w = wjA * e2A.w + wjB * e2B.w;

    // ---- cross-group reduction: sum over g (lanes xor 16, 32)
    #pragma unroll
    for (int d = 16; d <= 32; d <<= 1) {
        ssum  += __shfl_xor(ssum,  d);
        av0.x += __shfl_xor(av0.x, d); av0.y += __shfl_xor(av0.y, d);
        av0.z += __shfl_xor(av0.z, d); av0.w += __shfl_xor(av0.w, d);
        av1.x += __shfl_xor(av1.x, d); av1.y += __shfl_xor(av1.y, d);
        av1.z += __shfl_xor(av1.z, d); av1.w += __shfl_xor(av1.w, d);
        aeA.x += __shfl_xor(aeA.x, d); aeA.y += __shfl_xor(aeA.y, d);
        aeA.z += __shfl_xor(aeA.z, d); aeA.w += __shfl_xor(aeA.w, d);
        aeB.x += __shfl_xor(aeB.x, d); aeB.y += __shfl_xor(aeB.y, d);
        aeB.z += __shfl_xor(aeB.z, d); aeB.w += __shfl_xor(aeB.w, d);
        aeC.x += __shfl_xor(aeC.x, d); aeC.y += __shfl_xor(aeC.y, d);
        aeC.z += __shfl_xor(aeC.z, d); aeC.w += __shfl_xor(aeC.w, d);
    }

    // ---- atomic partial-sum epilogue (lanes of group 0)
    if (g == 0) {
        float* pv = sav + (size_t)n * HC_ + eh * 32 + si * 8;
        atomicAdd(pv + 0, av0.x); atomicAdd(pv + 1, av0.y);
        atomicAdd(pv + 2, av0.z); atomicAdd(pv + 3, av0.w);
        atomicAdd(pv + 4, av1.x); atomicAdd(pv + 5, av1.y);
        atomicAdd(pv + 6, av1.z); atomicAdd(pv + 7, av1.w);
        float* pe = sae + (size_t)n * 176 + eh * 44 + si * 12;
        atomicAdd(pe + 0, aeA.x); atomicAdd(pe + 1, aeA.y);
        atomicAdd(pe + 2, aeA.z); atomicAdd(pe + 3, aeA.w);
        atomicAdd(pe + 4, aeB.x); atomicAdd(pe + 5, aeB.y);
        atomicAdd(pe + 6, aeB.z); atomicAdd(pe + 7, aeB.w);
        if (si < 3) {
            atomicAdd(pe + 8,  aeC.x); atomicAdd(pe + 9,  aeC.y);
            atomicAdd(pe + 10, aeC.z); atomicAdd(pe + 11, aeC.w);
        }
        if (si == 0) atomicAdd(sbuf + (size_t)n * 4 + eh, ssum);
    }
}

// ---------------- finalize: out = (sav + sae@We)/s + skip   (wave per node)
__global__ __launch_bounds__(512) void k_fin(
    const float* __restrict__ sav, const float* __restrict__ sae,
    const float* __restrict__ sbuf, const float* __restrict__ We,
    const float* __restrict__ skip, float* __restrict__ out)
{
    const int t = threadIdx.x, w = t >> 6, l = t & 63;
    const int n = blockIdx.x * 8 + w;
    if (n >= N_) return;
    const int h2 = l >> 4;
    float2 acc = ((const float2*)(sav + (size_t)n * HC_))[l];
    const float* ae = sae + (size_t)n * 176 + h2 * 44;
    float evx = 0.f, evy = 0.f;
    for (int d = 0; d < ED_; ++d) {
        float aw = ae[d];
        float2 wd = ((const float2*)(We + d * HC_))[l];
        evx += aw * wd.x;
        evy += aw * wd.y;
    }
    float inv = 1.0f / (sbuf[(size_t)n * 4 + h2] + 1e-16f);
    float2 sk = ((const float2*)(skip + (size_t)n * HC_))[l];
    ((float2*)(out + (size_t)n * HC_))[l] =
        make_float2((acc.x + evx) * inv + sk.x, (acc.y + evy) * inv + sk.y);
}

extern "C" void kernel_launch(void* const* d_in, const int* in_sizes, int n_in,
                              void* d_out, int out_size, void* d_ws, size_t ws_size,
                              hipStream_t stream)
{
    const float* x   = (const float*)d_in[0];
    const int*   ei  = (const int*)d_in[1];
    const float* ea  = (const float*)d_in[2];
    const float* Wq  = (const float*)d_in[3];
    const float* bq  = (const float*)d_in[4];
    const float* Wk  = (const float*)d_in[5];
    const float* bk  = (const float*)d_in[6];
    const float* Wv  = (const float*)d_in[7];
    const float* bv  = (const float*)d_in[8];
    const float* We  = (const float*)d_in[9];
    const float* Wsk = (const float*)d_in[10];
    const float* bsk = (const float*)d_in[11];
    float* out = (float*)d_out;

    float* ws     = (float*)d_ws;
    float* q      = ws;                              // N*128
    float* k      = q    + (size_t)N_ * HC_;         // N*128
    float* v      = k    + (size_t)N_ * HC_;         // N*128
    float* skip   = v    + (size_t)N_ * HC_;         // N*128
    float* sav    = skip + (size_t)N_ * HC_;         // N*128 (atomic)
    float* sae    = sav  + (size_t)N_ * HC_;         // N*4*44 (atomic)
    float* sbuf   = sae  + (size_t)N_ * 176;         // N*4   (atomic)
    int*   cnt    = (int*)(sbuf + (size_t)N_ * 4);   // N
    int*   chcnt  = cnt + N_;                        // 1
    int*   chlist = chcnt + 1;                       // LCAP
    int*   csr    = chlist + LCAP_;                  // N*DEGCAP (edge ids)

    hipMemsetAsync(cnt, 0, (N_ + 1) * sizeof(int), stream);   // cnt + chcnt
    hipMemsetAsync(sav, 0, (size_t)N_ * (HC_ + 176 + 4) * sizeof(float), stream);
    k_lin    <<<dim3((N_ + 31) / 32, 4), 256, 0, stream>>>(
        x, Wq, bq, Wk, bk, Wv, bv, Wsk, bsk, q, k, v, skip);
    k_scatter<<<E_ / 256, 256, 0, stream>>>(ei, cnt, csr);
    k_chunks <<<(N_ + 255) / 256, 256, 0, stream>>>(cnt, chcnt, chlist);
    k_node   <<<LCAP_ / 8, 512, 0, stream>>>(chcnt, chlist, cnt, csr, ei, ea,
                                             We, q, k, v, sav, sae, sbuf);
    k_fin    <<<(N_ + 7) / 8, 512, 0, stream>>>(sav, sae, sbuf, We, skip, out);
}

// Round 8
// 1002.923 us; speedup vs baseline: 2.0713x; 2.0713x over previous
//
#include <hip/hip_runtime.h>

#define N_      50000
#define E_      800000
#define HC_     128
#define ED_     44
#define NH_     4
#define DEGCAP_ 96   // Poisson(16); P(deg>96) astronomically small

// ---------------- x @ {Wq,Wk,Wv,Wsk} + b : no-LDS, broadcast-x design.
// 32-lane group owns one row n; lane c owns out cols 4c..4c+3 for ALL 4 mats
// (16 indep acc chains). x[n,d] is a same-address broadcast load (L1);
// W is a linear 256KB stream (L2-resident, shared via L1 by the block's 8
// row-groups). No barriers -> compiler pipelines loads freely; 6250 blocks.
__global__ __launch_bounds__(256) void k_lin(
    const float* __restrict__ x,
    const float* __restrict__ Wq, const float* __restrict__ bq,
    const float* __restrict__ Wk, const float* __restrict__ bk,
    const float* __restrict__ Wv, const float* __restrict__ bv,
    const float* __restrict__ Wsk, const float* __restrict__ bsk,
    float* __restrict__ q, float* __restrict__ k, float* __restrict__ v,
    float* __restrict__ skip)
{
    const int t = threadIdx.x;
    const int r = t >> 5, c = t & 31;
    const int n = blockIdx.x * 8 + r;          // N_ = 50000 = 6250*8 exact

    const float4* x4  = (const float4*)(x + (size_t)n * HC_);
    const float4* Wq4 = (const float4*)Wq;
    const float4* Wk4 = (const float4*)Wk;
    const float4* Wv4 = (const float4*)Wv;
    const float4* Ws4 = (const float4*)Wsk;

    float4 aq = make_float4(0.f, 0.f, 0.f, 0.f);
    float4 ak = make_float4(0.f, 0.f, 0.f, 0.f);
    float4 av = make_float4(0.f, 0.f, 0.f, 0.f);
    float4 as = make_float4(0.f, 0.f, 0.f, 0.f);

    #pragma unroll 4
    for (int d4 = 0; d4 < 32; ++d4) {
        const float4 xv = x4[d4];
        #pragma unroll
        for (int dd = 0; dd < 4; ++dd) {
            const float xs = dd == 0 ? xv.x : dd == 1 ? xv.y : dd == 2 ? xv.z : xv.w;
            const int wi = (d4 * 4 + dd) * 32 + c;
            const float4 wq = Wq4[wi];
            const float4 wk = Wk4[wi];
            const float4 wv = Wv4[wi];
            const float4 ws = Ws4[wi];
            aq.x += xs * wq.x; aq.y += xs * wq.y; aq.z += xs * wq.z; aq.w += xs * wq.w;
            ak.x += xs * wk.x; ak.y += xs * wk.y; ak.z += xs * wk.z; ak.w += xs * wk.w;
            av.x += xs * wv.x; av.y += xs * wv.y; av.z += xs * wv.z; av.w += xs * wv.w;
            as.x += xs * ws.x; as.y += xs * ws.y; as.z += xs * ws.z; as.w += xs * ws.w;
        }
    }

    const float4 b0 = ((const float4*)bq)[c];
    const float4 b1 = ((const float4*)bk)[c];
    const float4 b2 = ((const float4*)bv)[c];
    const float4 b3 = ((const float4*)bsk)[c];
    ((float4*)(q    + (size_t)n * HC_))[c] =
        make_float4(aq.x + b0.x, aq.y + b0.y, aq.z + b0.z, aq.w + b0.w);
    ((float4*)(k    + (size_t)n * HC_))[c] =
        make_float4(ak.x + b1.x, ak.y + b1.y, ak.z + b1.z, ak.w + b1.w);
    ((float4*)(v    + (size_t)n * HC_))[c] =
        make_float4(av.x + b2.x, av.y + b2.y, av.z + b2.z, av.w + b2.w);
    ((float4*)(skip + (size_t)n * HC_))[c] =
        make_float4(as.x + b3.x, as.y + b3.y, as.z + b3.z, as.w + b3.w);
}

// --------------------------- padded-CSR build: one atomic pass, no scan
__global__ __launch_bounds__(256) void k_scatter(const int* __restrict__ ei,
                                                 int* __restrict__ cnt,
                                                 int2* __restrict__ csr) {
    int e = blockIdx.x * 256 + threadIdx.x;   // E_ divisible by 256
    int src = ei[e], dst = ei[E_ + e];
    int pos = atomicAdd(&cnt[dst], 1);
    if (pos < DEGCAP_) csr[(size_t)dst * DEGCAP_ + pos] = make_int2(src, e);
}

// ------------- wave-per-node, single-pass deferred normalization,
// 8 edges (2x4 chunks) per iteration with ALL 14 float4 gathers issued as
// straight-line named scalars BEFORE any consumption. (r6 verbatim: 334us.)
__global__ __launch_bounds__(256) void k_node(
    const int* __restrict__ cnt, const int2* __restrict__ csr,
    const float* __restrict__ ea, const float* __restrict__ We,
    const float* __restrict__ q, const float* __restrict__ k,
    const float* __restrict__ v, const float* __restrict__ skip,
    float* __restrict__ out)
{
    __shared__ float sq [4][128];   // q-row staging
    __shared__ float sqw[4][176];   // qwe[h][d], stride 44
    __shared__ float srd[4][324];   // 0..127 sav | 128..319 sae (48/head) | 320..323 s
    const int t = threadIdx.x, w = t >> 6, l = t & 63;
    const int n = blockIdx.x * 4 + w;

    // ---- stage q row (wave-private LDS)
    float2 q2 = ((const float2*)(q + (size_t)n * HC_))[l];
    ((float2*)&sq[w][0])[l] = q2;

    // ---- inline qWe: lane (h=l>>4, i16=l&15) -> dims 3*i16..+2 of head h
    {
        const int h = l >> 4, i16 = l & 15;
        const int d0 = 3 * i16;
        const int de0 = (d0     < ED_) ? d0     : ED_ - 1;
        const int de1 = (d0 + 1 < ED_) ? d0 + 1 : ED_ - 1;
        const int de2 = (d0 + 2 < ED_) ? d0 + 2 : ED_ - 1;
        const float* qh  = &sq[w][h * 32];
        const float* w0p = We + de0 * HC_ + h * 32;
        const float* w1p = We + de1 * HC_ + h * 32;
        const float* w2p = We + de2 * HC_ + h * 32;
        float qw0 = 0.f, qw1 = 0.f, qw2 = 0.f;
        #pragma unroll
        for (int i = 0; i < 8; ++i) {
            float4 q4 = *(const float4*)(qh  + i * 4);
            float4 a0 = *(const float4*)(w0p + i * 4);
            float4 a1 = *(const float4*)(w1p + i * 4);
            float4 a2 = *(const float4*)(w2p + i * 4);
            qw0 += q4.x*a0.x + q4.y*a0.y + q4.z*a0.z + q4.w*a0.w;
            qw1 += q4.x*a1.x + q4.y*a1.y + q4.z*a1.z + q4.w*a1.w;
            qw2 += q4.x*a2.x + q4.y*a2.y + q4.z*a2.z + q4.w*a2.w;
        }
        if (d0     < ED_) sqw[w][h * ED_ + d0]     = qw0;
        if (d0 + 1 < ED_) sqw[w][h * ED_ + d0 + 1] = qw1;
        if (d0 + 2 < ED_) sqw[w][h * ED_ + d0 + 2] = qw2;
    }

    // ---- edge-loop lane roles: g=l>>4 (edge in chunk), eh=head, si=sublane
    const int g = l >> 4, ii = l & 15, eh = ii >> 2, si = ii & 3;
    const float4 qa = *(const float4*)&sq[w][eh * 32 + si * 8];
    const float4 qb = *(const float4*)&sq[w][eh * 32 + si * 8 + 4];
    float4 w0, w1, w2;
    {   // qwe fragment: si<3 -> dims [si*12,+12); si==3 -> [36,+8) + zero
        const float* wp = &sqw[w][eh * ED_ + si * 12];
        w0 = *(const float4*)wp;
        w1 = *(const float4*)(wp + 4);
        w2 = (si < 3) ? *(const float4*)(wp + 8) : make_float4(0.f,0.f,0.f,0.f);
    }
    const int eoff2 = (si < 3) ? si * 12 + 8 : 36;

    int deg = cnt[n];
    deg = deg < DEGCAP_ ? deg : DEGCAP_;
    const int2* crow = csr + (size_t)n * DEGCAP_;
    int2 c0 = make_int2(0, 0);
    if (deg > 0) c0 = crow[l < deg ? l : deg - 1];

    float4 av0 = make_float4(0.f,0.f,0.f,0.f), av1 = make_float4(0.f,0.f,0.f,0.f);
    float4 aeA = make_float4(0.f,0.f,0.f,0.f), aeB = make_float4(0.f,0.f,0.f,0.f);
    float4 aeC = make_float4(0.f,0.f,0.f,0.f);
    float ssum = 0.f;

    const int lim = deg < 64 ? deg : 64;
    for (int base = 0; base < lim; base += 8) {
        const int slotA = base + g,     slotB = base + 4 + g;
        const int scA = slotA < lim ? slotA : lim - 1;
        const int scB = slotB < lim ? slotB : lim - 1;
        const int sA = __shfl(c0.x, scA), eEA = __shfl(c0.y, scA);
        const int sB = __shfl(c0.x, scB), eEB = __shfl(c0.y, scB);

        // ---------- load block: 14 independent float4 gathers, no consumers
        const float* kpA = k + (size_t)sA * HC_ + eh * 32 + si * 8;
        const float* vpA = v + (size_t)sA * HC_ + eh * 32 + si * 8;
        const float* epA = ea + (size_t)eEA * ED_;
        const float* kpB = k + (size_t)sB * HC_ + eh * 32 + si * 8;
        const float* vpB = v + (size_t)sB * HC_ + eh * 32 + si * 8;
        const float* epB = ea + (size_t)eEB * ED_;
        const float4 kaA = *(const float4*)kpA;
        const float4 kbA = *(const float4*)(kpA + 4);
        const float4 vaA = *(const float4*)vpA;
        const float4 vbA = *(const float4*)(vpA + 4);
        const float4 e0A = *(const float4*)(epA + si * 12);
        const float4 e1A = *(const float4*)(epA + si * 12 + 4);
        const float4 e2A = *(const float4*)(epA + eoff2);
        const float4 kaB = *(const float4*)kpB;
        const float4 kbB = *(const float4*)(kpB + 4);
        const float4 vaB = *(const float4*)vpB;
        const float4 vbB = *(const float4*)(vpB + 4);
        const float4 e0B = *(const float4*)(epB + si * 12);
        const float4 e1B = *(const float4*)(epB + si * 12 + 4);
        const float4 e2B = *(const float4*)(epB + eoff2);

        // ---------- compute A
        float pA = qa.x*kaA.x + qa.y*kaA.y + qa.z*kaA.z + qa.w*kaA.w
                 + qb.x*kbA.x + qb.y*kbA.y + qb.z*kbA.z + qb.w*kbA.w
                 + w0.x*e0A.x + w0.y*e0A.y + w0.z*e0A.z + w0.w*e0A.w
                 + w1.x*e1A.x + w1.y*e1A.y + w1.z*e1A.z + w1.w*e1A.w
                 + w2.x*e2A.x + w2.y*e2A.y + w2.z*e2A.z + w2.w*e2A.w;
        // ---------- compute B (independent shfl chains interleave)
        float pB = qa.x*kaB.x + qa.y*kaB.y + qa.z*kaB.z + qa.w*kaB.w
                 + qb.x*kbB.x + qb.y*kbB.y + qb.z*kbB.z + qb.w*kbB.w
                 + w0.x*e0B.x + w0.y*e0B.y + w0.z*e0B.z + w0.w*e0B.w
                 + w1.x*e1B.x + w1.y*e1B.y + w1.z*e1B.z + w1.w*e1B.w
                 + w2.x*e2B.x + w2.y*e2B.y + w2.z*e2B.z + w2.w*e2B.w;
        pA += __shfl_xor(pA, 1);  pB += __shfl_xor(pB, 1);
        pA += __shfl_xor(pA, 2);  pB += __shfl_xor(pB, 2);
        const float alA = fminf(pA * 0.17677669529663687f, 40.f);
        const float alB = fminf(pB * 0.17677669529663687f, 40.f);
        const float wjA = (slotA < lim) ? __expf(alA) : 0.f;
        const float wjB = (slotB < lim) ? __expf(alB) : 0.f;

        ssum  += wjA + wjB;
        av0.x += wjA * vaA.x + wjB * vaB.x;  av0.y += wjA * vaA.y + wjB * vaB.y;
        av0.z += wjA * vaA.z + wjB * vaB.z;  av0.w += wjA * vaA.w + wjB * vaB.w;
        av1.x += wjA * vbA.x + wjB * vbB.x;  av1.y += wjA * vbA.y + wjB * vbB.y;
        av1.z += wjA * vbA.z + wjB * vbB.z;  av1.w += wjA * vbA.w + wjB * vbB.w;
        aeA.x += wjA * e0A.x + wjB * e0B.x;  aeA.y += wjA * e0A.y + wjB * e0B.y;
        aeA.z += wjA * e0A.z + wjB * e0B.z;  aeA.w += wjA * e0A.w + wjB * e0B.w;
        aeB.x += wjA * e1A.x + wjB * e1B.x;  aeB.y += wjA * e1A.y + wjB * e1B.y;
        aeB.z += wjA * e1A.z + wjB * e1B.z;  aeB.w += wjA * e1A.w + wjB * e1B.w;
        aeC.x += wjA * e2A.x + wjB * e2B.x;  aeC.y += wjA * e2A.y + wjB * e2B.y;
        aeC.z += wjA * e2A.z + wjB * e2B.z;  aeC.w += wjA * e2A.w + wjB * e2B.w;
    }

    // ---- rare deg>64 tail: wave-uniform single-edge steps
    for (int j = 64; j < deg; ++j) {
        int2 se = crow[j];
        int sA = __builtin_amdgcn_readfirstlane(se.x);
        int eA = __builtin_amdgcn_readfirstlane(se.y);
        const float* kp = k + (size_t)sA * HC_ + eh * 32 + si * 8;
        const float* vp = v + (size_t)sA * HC_ + eh * 32 + si * 8;
        const float* ep = ea + (size_t)eA * ED_;
        float4 ka = *(const float4*)kp, kb = *(const float4*)(kp + 4);
        float4 va = *(const float4*)vp, vb = *(const float4*)(vp + 4);
        float4 e0 = *(const float4*)(ep + si * 12);
        float4 e1 = *(const float4*)(ep + si * 12 + 4);
        float4 e2 = *(const float4*)(ep + eoff2);
        float p = qa.x*ka.x + qa.y*ka.y + qa.z*ka.z + qa.w*ka.w
                + qb.x*kb.x + qb.y*kb.y + qb.z*kb.z + qb.w*kb.w
                + w0.x*e0.x + w0.y*e0.y + w0.z*e0.z + w0.w*e0.w
                + w1.x*e1.x + w1.y*e1.y + w1.z*e1.z + w1.w*e1.w
                + w2.x*e2.x + w2.y*e2.y + w2.z*e2.z + w2.w*e2.w;
        p += __shfl_xor(p, 1);
        p += __shfl_xor(p, 2);
        float wj = (g == 0) ? __expf(fminf(p * 0.17677669529663687f, 40.f)) : 0.f;
        ssum  += wj;
        av0.x += wj * va.x; av0.y += wj * va.y; av0.z += wj * va.z; av0.w += wj * va.w;
        av1.x += wj * vb.x; av1.y += wj * vb.y; av1.z += wj * vb.z; av1.w += wj * vb.w;
        aeA.x += wj * e0.x; aeA.y += wj * e0.y; aeA.z += wj * e0.z; aeA.w += wj * e0.w;
        aeB.x += wj * e1.x; aeB.y += wj * e1.y; aeB.z += wj * e1.z; aeB.w += wj * e1.w;
        aeC.x += wj * e2.x; aeC.y += wj * e2.y; aeC.z += wj * e2.z; aeC.w += wj * e2.w;
    }

    // ---- cross-group reduction: sum over g (lanes xor 16, 32)
    #pragma unroll
    for (int d = 16; d <= 32; d <<= 1) {
        ssum  += __shfl_xor(ssum,  d);
        av0.x += __shfl_xor(av0.x, d); av0.y += __shfl_xor(av0.y, d);
        av0.z += __shfl_xor(av0.z, d); av0.w += __shfl_xor(av0.w, d);
        av1.x += __shfl_xor(av1.x, d); av1.y += __shfl_xor(av1.y, d);
        av1.z += __shfl_xor(av1.z, d); av1.w += __shfl_xor(av1.w, d);
        aeA.x += __shfl_xor(aeA.x, d); aeA.y += __shfl_xor(aeA.y, d);
        aeA.z += __shfl_xor(aeA.z, d); aeA.w += __shfl_xor(aeA.w, d);
        aeB.x += __shfl_xor(aeB.x, d); aeB.y += __shfl_xor(aeB.y, d);
        aeB.z += __shfl_xor(aeB.z, d); aeB.w += __shfl_xor(aeB.w, d);
        aeC.x += __shfl_xor(aeC.x, d); aeC.y += __shfl_xor(aeC.y, d);
        aeC.z += __shfl_xor(aeC.z, d); aeC.w += __shfl_xor(aeC.w, d);
    }

    // ---- stage sums (g==0 lanes): sav channels, sae dims (48/head), s
    float* sav = &srd[w][0];
    float* sae = &srd[w][128];
    float* ssm = &srd[w][320];
    if (g == 0) {
        *(float4*)&sav[eh * 32 + si * 8]     = av0;
        *(float4*)&sav[eh * 32 + si * 8 + 4] = av1;
        *(float4*)&sae[eh * 48 + si * 12]     = aeA;
        *(float4*)&sae[eh * 48 + si * 12 + 4] = aeB;
        if (si < 3) *(float4*)&sae[eh * 48 + si * 12 + 8] = aeC;
        if (si == 0) ssm[eh] = ssum;
    }

    // ---- epilogue: channel role c = 2l; We contraction + divide + skip
    const int h2 = l >> 4;
    float2 acc = *(const float2*)&sav[2 * l];
    float evx = 0.f, evy = 0.f;
    for (int d = 0; d < ED_; ++d) {
        float aw = sae[h2 * 48 + d];
        float2 wd = ((const float2*)(We + d * HC_))[l];
        evx += aw * wd.x;
        evy += aw * wd.y;
    }
    float inv = 1.0f / (ssm[h2] + 1e-16f);
    float2 sk = ((const float2*)(skip + (size_t)n * HC_))[l];
    ((float2*)(out + (size_t)n * HC_))[l] =
        make_float2((acc.x + evx) * inv + sk.x, (acc.y + evy) * inv + sk.y);
}

extern "C" void kernel_launch(void* const* d_in, const int* in_sizes, int n_in,
                              void* d_out, int out_size, void* d_ws, size_t ws_size,
                              hipStream_t stream)
{
    const float* x   = (const float*)d_in[0];
    const int*   ei  = (const int*)d_in[1];
    const float* ea  = (const float*)d_in[2];
    const float* Wq  = (const float*)d_in[3];
    const float* bq  = (const float*)d_in[4];
    const float* Wk  = (const float*)d_in[5];
    const float* bk  = (const float*)d_in[6];
    const float* Wv  = (const float*)d_in[7];
    const float* bv  = (const float*)d_in[8];
    const float* We  = (const float*)d_in[9];
    const float* Wsk = (const float*)d_in[10];
    const float* bsk = (const float*)d_in[11];
    float* out = (float*)d_out;

    float* ws    = (float*)d_ws;
    float* q     = ws;                             // N*128
    float* k     = q     + (size_t)N_ * HC_;       // N*128
    float* v     = k     + (size_t)N_ * HC_;       // N*128
    float* skip  = v     + (size_t)N_ * HC_;       // N*128
    int*   cnt   = (int*)(skip + (size_t)N_ * HC_); // N
    int2*  csr   = (int2*)(cnt + N_);              // N*DEGCAP

    hipMemsetAsync(cnt, 0, N_ * sizeof(int), stream);
    k_lin    <<<N_ / 8, 256, 0, stream>>>(x, Wq, bq, Wk, bk, Wv, bv,
                                          Wsk, bsk, q, k, v, skip);
    k_scatter<<<E_ / 256, 256, 0, stream>>>(ei, cnt, csr);
    k_node   <<<N_ / 4, 256, 0, stream>>>(cnt, csr, ea, We, q, k, v,
                                          skip, out);
}

// Round 9
// 722.356 us; speedup vs baseline: 2.8759x; 1.3884x over previous
//
#include <hip/hip_runtime.h>

#define N_      50000
#define E_      800000
#define HC_     128
#define ED_     44
#define NH_     4
#define DEGCAP_ 96   // Poisson(16); P(deg>96) astronomically small

// ---------------- x @ W[mat] + b : 32-row tile, one mat per block (grid.y).
// 2-step-deep W prefetch: 8 float4 in flight, issued ~256 VALU-cycles before
// consumption (covers L2 ~200-300cy; r3's 1-step ~128cy was the 25% VALUBusy).
// launch_bounds(256,4): VGPR cap 128 so the pipeline regs aren't squeezed.
__global__ __launch_bounds__(256, 4) void k_lin(
    const float* __restrict__ x,
    const float* __restrict__ Wq, const float* __restrict__ bq,
    const float* __restrict__ Wk, const float* __restrict__ bk,
    const float* __restrict__ Wv, const float* __restrict__ bv,
    const float* __restrict__ Wsk, const float* __restrict__ bsk,
    float* __restrict__ q, float* __restrict__ k, float* __restrict__ v,
    float* __restrict__ skip)
{
    __shared__ float xs[32 * 128];    // 16 KB
    const int n0 = blockIdx.x * 32;
    const int t  = threadIdx.x;

    #pragma unroll
    for (int i = 0; i < 4; ++i) {
        int idx = t + i * 256;        // float4 index, 0..1023
        int row = idx >> 5;
        float4 a = make_float4(0.f, 0.f, 0.f, 0.f);
        if (n0 + row < N_) a = ((const float4*)x)[(size_t)n0 * 32 + idx];
        *(float4*)&xs[idx * 4] = a;
    }
    __syncthreads();

    const float* Wm[4] = {Wq, Wk, Wv, Wsk};
    const float* bm[4] = {bq, bk, bv, bsk};
    float* om[4] = {q, k, v, skip};
    const int mat = blockIdx.y;
    const float* W = Wm[mat];

    const int tx = t & 31, ty = t >> 5;
    float acc[4][4];
    #pragma unroll
    for (int r = 0; r < 4; ++r) {
        acc[r][0] = 0.f; acc[r][1] = 0.f; acc[r][2] = 0.f; acc[r][3] = 0.f;
    }

    // prefetch steps 0 and 1
    float4 wb0[4], wb1[4];
    #pragma unroll
    for (int dd = 0; dd < 4; ++dd) {
        wb0[dd] = *(const float4*)(W + (dd)     * 128 + tx * 4);
        wb1[dd] = *(const float4*)(W + (4 + dd) * 128 + tx * 4);
    }

    for (int s = 0; s < 32; s += 2) {
        const int sp0 = (s + 2) & 31, sp1 = (s + 3) & 31;  // wrap: harmless L1-hot reload
        float4 wn0[4], wn1[4];
        #pragma unroll
        for (int dd = 0; dd < 4; ++dd)
            wn0[dd] = *(const float4*)(W + (sp0 * 4 + dd) * 128 + tx * 4);
        #pragma unroll
        for (int dd = 0; dd < 4; ++dd)
            wn1[dd] = *(const float4*)(W + (sp1 * 4 + dd) * 128 + tx * 4);

        #pragma unroll
        for (int r = 0; r < 4; ++r) {
            float4 xv = *(const float4*)&xs[(ty * 4 + r) * 128 + s * 4];
            acc[r][0] += xv.x * wb0[0].x + xv.y * wb0[1].x + xv.z * wb0[2].x + xv.w * wb0[3].x;
            acc[r][1] += xv.x * wb0[0].y + xv.y * wb0[1].y + xv.z * wb0[2].y + xv.w * wb0[3].y;
            acc[r][2] += xv.x * wb0[0].z + xv.y * wb0[1].z + xv.z * wb0[2].z + xv.w * wb0[3].z;
            acc[r][3] += xv.x * wb0[0].w + xv.y * wb0[1].w + xv.z * wb0[2].w + xv.w * wb0[3].w;
        }
        #pragma unroll
        for (int r = 0; r < 4; ++r) {
            float4 xv = *(const float4*)&xs[(ty * 4 + r) * 128 + (s + 1) * 4];
            acc[r][0] += xv.x * wb1[0].x + xv.y * wb1[1].x + xv.z * wb1[2].x + xv.w * wb1[3].x;
            acc[r][1] += xv.x * wb1[0].y + xv.y * wb1[1].y + xv.z * wb1[2].y + xv.w * wb1[3].y;
            acc[r][2] += xv.x * wb1[0].z + xv.y * wb1[1].z + xv.z * wb1[2].z + xv.w * wb1[3].z;
            acc[r][3] += xv.x * wb1[0].w + xv.y * wb1[1].w + xv.z * wb1[2].w + xv.w * wb1[3].w;
        }
        #pragma unroll
        for (int dd = 0; dd < 4; ++dd) { wb0[dd] = wn0[dd]; wb1[dd] = wn1[dd]; }
    }

    float4 b4 = *(const float4*)(bm[mat] + tx * 4);
    float* o = om[mat];
    #pragma unroll
    for (int r = 0; r < 4; ++r) {
        int n = n0 + ty * 4 + r;
        if (n < N_) {
            float4 rr = make_float4(acc[r][0] + b4.x, acc[r][1] + b4.y,
                                    acc[r][2] + b4.z, acc[r][3] + b4.w);
            ((float4*)(o + (size_t)n * 128))[tx] = rr;
        }
    }
}

// --------------------------- padded-CSR build: one atomic pass, no scan
__global__ __launch_bounds__(256) void k_scatter(const int* __restrict__ ei,
                                                 int* __restrict__ cnt,
                                                 int2* __restrict__ csr) {
    int e = blockIdx.x * 256 + threadIdx.x;   // E_ divisible by 256
    int src = ei[e], dst = ei[E_ + e];
    int pos = atomicAdd(&cnt[dst], 1);
    if (pos < DEGCAP_) csr[(size_t)dst * DEGCAP_ + pos] = make_int2(src, e);
}

// ------------- wave-per-node, single-pass deferred normalization (r6 code).
// launch_bounds(256,2): VGPR cap 256 (default 8-waves/EU target capped the
// allocator at 64 VGPR and made the scheduler SINK the 14-load block; the
// measured residency is only ~2.5 waves/SIMD, so the budget was pure waste).
__global__ __launch_bounds__(256, 2) void k_node(
    const int* __restrict__ cnt, const int2* __restrict__ csr,
    const float* __restrict__ ea, const float* __restrict__ We,
    const float* __restrict__ q, const float* __restrict__ k,
    const float* __restrict__ v, const float* __restrict__ skip,
    float* __restrict__ out)
{
    __shared__ float sq [4][128];   // q-row staging
    __shared__ float sqw[4][176];   // qwe[h][d], stride 44
    __shared__ float srd[4][324];   // 0..127 sav | 128..319 sae (48/head) | 320..323 s
    const int t = threadIdx.x, w = t >> 6, l = t & 63;
    const int n = blockIdx.x * 4 + w;

    // ---- stage q row (wave-private LDS)
    float2 q2 = ((const float2*)(q + (size_t)n * HC_))[l];
    ((float2*)&sq[w][0])[l] = q2;

    // ---- inline qWe: lane (h=l>>4, i16=l&15) -> dims 3*i16..+2 of head h
    {
        const int h = l >> 4, i16 = l & 15;
        const int d0 = 3 * i16;
        const int de0 = (d0     < ED_) ? d0     : ED_ - 1;
        const int de1 = (d0 + 1 < ED_) ? d0 + 1 : ED_ - 1;
        const int de2 = (d0 + 2 < ED_) ? d0 + 2 : ED_ - 1;
        const float* qh  = &sq[w][h * 32];
        const float* w0p = We + de0 * HC_ + h * 32;
        const float* w1p = We + de1 * HC_ + h * 32;
        const float* w2p = We + de2 * HC_ + h * 32;
        float qw0 = 0.f, qw1 = 0.f, qw2 = 0.f;
        #pragma unroll
        for (int i = 0; i < 8; ++i) {
            float4 q4 = *(const float4*)(qh  + i * 4);
            float4 a0 = *(const float4*)(w0p + i * 4);
            float4 a1 = *(const float4*)(w1p + i * 4);
            float4 a2 = *(const float4*)(w2p + i * 4);
            qw0 += q4.x*a0.x + q4.y*a0.y + q4.z*a0.z + q4.w*a0.w;
            qw1 += q4.x*a1.x + q4.y*a1.y + q4.z*a1.z + q4.w*a1.w;
            qw2 += q4.x*a2.x + q4.y*a2.y + q4.z*a2.z + q4.w*a2.w;
        }
        if (d0     < ED_) sqw[w][h * ED_ + d0]     = qw0;
        if (d0 + 1 < ED_) sqw[w][h * ED_ + d0 + 1] = qw1;
        if (d0 + 2 < ED_) sqw[w][h * ED_ + d0 + 2] = qw2;
    }

    // ---- edge-loop lane roles: g=l>>4 (edge in chunk), eh=head, si=sublane
    const int g = l >> 4, ii = l & 15, eh = ii >> 2, si = ii & 3;
    const float4 qa = *(const float4*)&sq[w][eh * 32 + si * 8];
    const float4 qb = *(const float4*)&sq[w][eh * 32 + si * 8 + 4];
    float4 w0, w1, w2;
    {   // qwe fragment: si<3 -> dims [si*12,+12); si==3 -> [36,+8) + zero
        const float* wp = &sqw[w][eh * ED_ + si * 12];
        w0 = *(const float4*)wp;
        w1 = *(const float4*)(wp + 4);
        w2 = (si < 3) ? *(const float4*)(wp + 8) : make_float4(0.f,0.f,0.f,0.f);
    }
    const int eoff2 = (si < 3) ? si * 12 + 8 : 36;

    int deg = cnt[n];
    deg = deg < DEGCAP_ ? deg : DEGCAP_;
    const int2* crow = csr + (size_t)n * DEGCAP_;
    int2 c0 = make_int2(0, 0);
    if (deg > 0) c0 = crow[l < deg ? l : deg - 1];

    float4 av0 = make_float4(0.f,0.f,0.f,0.f), av1 = make_float4(0.f,0.f,0.f,0.f);
    float4 aeA = make_float4(0.f,0.f,0.f,0.f), aeB = make_float4(0.f,0.f,0.f,0.f);
    float4 aeC = make_float4(0.f,0.f,0.f,0.f);
    float ssum = 0.f;

    const int lim = deg < 64 ? deg : 64;
    for (int base = 0; base < lim; base += 8) {
        const int slotA = base + g,     slotB = base + 4 + g;
        const int scA = slotA < lim ? slotA : lim - 1;
        const int scB = slotB < lim ? slotB : lim - 1;
        const int sA = __shfl(c0.x, scA), eEA = __shfl(c0.y, scA);
        const int sB = __shfl(c0.x, scB), eEB = __shfl(c0.y, scB);

        // ---------- load block: 14 independent float4 gathers, no consumers
        const float* kpA = k + (size_t)sA * HC_ + eh * 32 + si * 8;
        const float* vpA = v + (size_t)sA * HC_ + eh * 32 + si * 8;
        const float* epA = ea + (size_t)eEA * ED_;
        const float* kpB = k + (size_t)sB * HC_ + eh * 32 + si * 8;
        const float* vpB = v + (size_t)sB * HC_ + eh * 32 + si * 8;
        const float* epB = ea + (size_t)eEB * ED_;
        const float4 kaA = *(const float4*)kpA;
        const float4 kbA = *(const float4*)(kpA + 4);
        const float4 vaA = *(const float4*)vpA;
        const float4 vbA = *(const float4*)(vpA + 4);
        const float4 e0A = *(const float4*)(epA + si * 12);
        const float4 e1A = *(const float4*)(epA + si * 12 + 4);
        const float4 e2A = *(const float4*)(epA + eoff2);
        const float4 kaB = *(const float4*)kpB;
        const float4 kbB = *(const float4*)(kpB + 4);
        const float4 vaB = *(const float4*)vpB;
        const float4 vbB = *(const float4*)(vpB + 4);
        const float4 e0B = *(const float4*)(epB + si * 12);
        const float4 e1B = *(const float4*)(epB + si * 12 + 4);
        const float4 e2B = *(const float4*)(epB + eoff2);

        // ---------- compute A
        float pA = qa.x*kaA.x + qa.y*kaA.y + qa.z*kaA.z + qa.w*kaA.w
                 + qb.x*kbA.x + qb.y*kbA.y + qb.z*kbA.z + qb.w*kbA.w
                 + w0.x*e0A.x + w0.y*e0A.y + w0.z*e0A.z + w0.w*e0A.w
                 + w1.x*e1A.x + w1.y*e1A.y + w1.z*e1A.z + w1.w*e1A.w
                 + w2.x*e2A.x + w2.y*e2A.y + w2.z*e2A.z + w2.w*e2A.w;
        // ---------- compute B (independent shfl chains interleave)
        float pB = qa.x*kaB.x + qa.y*kaB.y + qa.z*kaB.z + qa.w*kaB.w
                 + qb.x*kbB.x + qb.y*kbB.y + qb.z*kbB.z + qb.w*kbB.w
                 + w0.x*e0B.x + w0.y*e0B.y + w0.z*e0B.z + w0.w*e0B.w
                 + w1.x*e1B.x + w1.y*e1B.y + w1.z*e1B.z + w1.w*e1B.w
                 + w2.x*e2B.x + w2.y*e2B.y + w2.z*e2B.z + w2.w*e2B.w;
        pA += __shfl_xor(pA, 1);  pB += __shfl_xor(pB, 1);
        pA += __shfl_xor(pA, 2);  pB += __shfl_xor(pB, 2);
        const float alA = fminf(pA * 0.17677669529663687f, 40.f);
        const float alB = fminf(pB * 0.17677669529663687f, 40.f);
        const float wjA = (slotA < lim) ? __expf(alA) : 0.f;
        const float wjB = (slotB < lim) ? __expf(alB) : 0.f;

        ssum  += wjA + wjB;
        av0.x += wjA * vaA.x + wjB * vaB.x;  av0.y += wjA * vaA.y + wjB * vaB.y;
        av0.z += wjA * vaA.z + wjB * vaB.z;  av0.w += wjA * vaA.w + wjB * vaB.w;
        av1.x += wjA * vbA.x + wjB * vbB.x;  av1.y += wjA * vbA.y + wjB * vbB.y;
        av1.z += wjA * vbA.z + wjB * vbB.z;  av1.w += wjA * vbA.w + wjB * vbB.w;
        aeA.x += wjA * e0A.x + wjB * e0B.x;  aeA.y += wjA * e0A.y + wjB * e0B.y;
        aeA.z += wjA * e0A.z + wjB * e0B.z;  aeA.w += wjA * e0A.w + wjB * e0B.w;
        aeB.x += wjA * e1A.x + wjB * e1B.x;  aeB.y += wjA * e1A.y + wjB * e1B.y;
        aeB.z += wjA * e1A.z + wjB * e1B.z;  aeB.w += wjA * e1A.w + wjB * e1B.w;
        aeC.x += wjA * e2A.x + wjB * e2B.x;  aeC.y += wjA * e2A.y + wjB * e2B.y;
        aeC.z += wjA * e2A.z + wjB * e2B.z;  aeC.w += wjA * e2A.w + wjB * e2B.w;
    }

    // ---- rare deg>64 tail: wave-uniform single-edge steps
    for (int j = 64; j < deg; ++j) {
        int2 se = crow[j];
        int sA = __builtin_amdgcn_readfirstlane(se.x);
        int eA = __builtin_amdgcn_readfirstlane(se.y);
        const float* kp = k + (size_t)sA * HC_ + eh * 32 + si * 8;
        const float* vp = v + (size_t)sA * HC_ + eh * 32 + si * 8;
        const float* ep = ea + (size_t)eA * ED_;
        float4 ka = *(const float4*)kp, kb = *(const float4*)(kp + 4);
        float4 va = *(const float4*)vp, vb = *(const float4*)(vp + 4);
        float4 e0 = *(const float4*)(ep + si * 12);
        float4 e1 = *(const float4*)(ep + si * 12 + 4);
        float4 e2 = *(const float4*)(ep + eoff2);
        float p = qa.x*ka.x + qa.y*ka.y + qa.z*ka.z + qa.w*ka.w
                + qb.x*kb.x + qb.y*kb.y + qb.z*kb.z + qb.w*kb.w
                + w0.x*e0.x + w0.y*e0.y + w0.z*e0.z + w0.w*e0.w
                + w1.x*e1.x + w1.y*e1.y + w1.z*e1.z + w1.w*e1.w
                + w2.x*e2.x + w2.y*e2.y + w2.z*e2.z + w2.w*e2.w;
        p += __shfl_xor(p, 1);
        p += __shfl_xor(p, 2);
        float wj = (g == 0) ? __expf(fminf(p * 0.17677669529663687f, 40.f)) : 0.f;
        ssum  += wj;
        av0.x += wj * va.x; av0.y += wj * va.y; av0.z += wj * va.z; av0.w += wj * va.w;
        av1.x += wj * vb.x; av1.y += wj * vb.y; av1.z += wj * vb.z; av1.w += wj * vb.w;
        aeA.x += wj * e0.x; aeA.y += wj * e0.y; aeA.z += wj * e0.z; aeA.w += wj * e0.w;
        aeB.x += wj * e1.x; aeB.y += wj * e1.y; aeB.z += wj * e1.z; aeB.w += wj * e1.w;
        aeC.x += wj * e2.x; aeC.y += wj * e2.y; aeC.z += wj * e2.z; aeC.w += wj * e2.w;
    }

    // ---- cross-group reduction: sum over g (lanes xor 16, 32)
    #pragma unroll
    for (int d = 16; d <= 32; d <<= 1) {
        ssum  += __shfl_xor(ssum,  d);
        av0.x += __shfl_xor(av0.x, d); av0.y += __shfl_xor(av0.y, d);
        av0.z += __shfl_xor(av0.z, d); av0.w += __shfl_xor(av0.w, d);
        av1.x += __shfl_xor(av1.x, d); av1.y += __shfl_xor(av1.y, d);
        av1.z += __shfl_xor(av1.z, d); av1.w += __shfl_xor(av1.w, d);
        aeA.x += __shfl_xor(aeA.x, d); aeA.y += __shfl_xor(aeA.y, d);
        aeA.z += __shfl_xor(aeA.z, d); aeA.w += __shfl_xor(aeA.w, d);
        aeB.x += __shfl_xor(aeB.x, d); aeB.y += __shfl_xor(aeB.y, d);
        aeB.z += __shfl_xor(aeB.z, d); aeB.w += __shfl_xor(aeB.w, d);
        aeC.x += __shfl_xor(aeC.x, d); aeC.y += __shfl_xor(aeC.y, d);
        aeC.z += __shfl_xor(aeC.z, d); aeC.w += __shfl_xor(aeC.w, d);
    }

    // ---- stage sums (g==0 lanes): sav channels, sae dims (48/head), s
    float* sav = &srd[w][0];
    float* sae = &srd[w][128];
    float* ssm = &srd[w][320];
    if (g == 0) {
        *(float4*)&sav[eh * 32 + si * 8]     = av0;
        *(float4*)&sav[eh * 32 + si * 8 + 4] = av1;
        *(float4*)&sae[eh * 48 + si * 12]     = aeA;
        *(float4*)&sae[eh * 48 + si * 12 + 4] = aeB;
        if (si < 3) *(float4*)&sae[eh * 48 + si * 12 + 8] = aeC;
        if (si == 0) ssm[eh] = ssum;
    }

    // ---- epilogue: channel role c = 2l; We contraction + divide + skip
    const int h2 = l >> 4;
    float2 acc = *(const float2*)&sav[2 * l];
    float evx = 0.f, evy = 0.f;
    for (int d = 0; d < ED_; ++d) {
        float aw = sae[h2 * 48 + d];
        float2 wd = ((const float2*)(We + d * HC_))[l];
        evx += aw * wd.x;
        evy += aw * wd.y;
    }
    float inv = 1.0f / (ssm[h2] + 1e-16f);
    float2 sk = ((const float2*)(skip + (size_t)n * HC_))[l];
    ((float2*)(out + (size_t)n * HC_))[l] =
        make_float2((acc.x + evx) * inv + sk.x, (acc.y + evy) * inv + sk.y);
}

extern "C" void kernel_launch(void* const* d_in, const int* in_sizes, int n_in,
                              void* d_out, int out_size, void* d_ws, size_t ws_size,
                              hipStream_t stream)
{
    const float* x   = (const float*)d_in[0];
    const int*   ei  = (const int*)d_in[1];
    const float* ea  = (const float*)d_in[2];
    const float* Wq  = (const float*)d_in[3];
    const float* bq  = (const float*)d_in[4];
    const float* Wk  = (const float*)d_in[5];
    const float* bk  = (const float*)d_in[6];
    const float* Wv  = (const float*)d_in[7];
    const float* bv  = (const float*)d_in[8];
    const float* We  = (const float*)d_in[9];
    const float* Wsk = (const float*)d_in[10];
    const float* bsk = (const float*)d_in[11];
    float* out = (float*)d_out;

    float* ws    = (float*)d_ws;
    float* q     = ws;                             // N*128
    float* k     = q     + (size_t)N_ * HC_;       // N*128
    float* v     = k     + (size_t)N_ * HC_;       // N*128
    float* skip  = v     + (size_t)N_ * HC_;       // N*128
    int*   cnt   = (int*)(skip + (size_t)N_ * HC_); // N
    int2*  csr   = (int2*)(cnt + N_);              // N*DEGCAP

    hipMemsetAsync(cnt, 0, N_ * sizeof(int), stream);
    k_lin    <<<dim3((N_ + 31) / 32, 4), 256, 0, stream>>>(
        x, Wq, bq, Wk, bk, Wv, bv, Wsk, bsk, q, k, v, skip);
    k_scatter<<<E_ / 256, 256, 0, stream>>>(ei, cnt, csr);
    k_node   <<<N_ / 4, 256, 0, stream>>>(cnt, csr, ea, We, q, k, v,
                                          skip, out);
}